// Round 12
// baseline (63.119 us; speedup 1.0000x reference)
//
#include <hip/hip_runtime.h>

// ROI-Align (bilinear, half-pixel) — B=1, H=W=128, C=512, POOL=7, N ROIs.
// Output layout: (N, 1, 7, 7, C) flat = ((roi*49 + py*7 + px) * C + c).
//
// Round-12: write-contiguity structure (A/B vs the channel-partitioned R4/R8).
//   Model from R11 profile: timed-replay HBM traffic is writes-only
//   (FETCH 18 MB, WRITE 100 MB), and 256B-per-XCD strided writes run at
//   ~3.2 TB/s — the 31 µs plateau. So:
//   - NO channel partition: each block computes 2 whole bins
//     (128 lanes x f32x4 = 512 ch) → 4 KB contiguous NT writes.
//   - Bin-pair swizzle: XCD k (= blockIdx.x % 8 round-robin) owns pairs
//     [k*3136, (k+1)*3136) → each XCD writes one contiguous 12.8 MB span,
//     fill-like DRAM locality.
//   - NT stores bypass cache allocation → the 33.5 MB feature map stays
//     L3-resident across graph replays; reads then come from L3, writes
//     own the HBM pins.

#define POOLN 7
#define FM_W 128
#define FM_C 512
#define NXCD 8

typedef float f32x4 __attribute__((ext_vector_type(4)));

__global__ __launch_bounds__(256) void roi_align_kernel(
    const float* __restrict__ fm,
    const int* __restrict__ rois,
    float* __restrict__ out,
    int pairs_per_xcd)                 // 3136
{
    // XCD-contiguous bin-pair swizzle (bijective: 8 * pairs_per_xcd pairs)
    const int xcd  = blockIdx.x & (NXCD - 1);
    const int j    = blockIdx.x >> 3;
    const int pair = xcd * pairs_per_xcd + j;

    const int sub  = threadIdx.x >> 7;           // 0,1 — bin within pair
    const int lane = threadIdx.x & 127;          // f32x4 channel index
    const int bin  = pair * 2 + sub;

    const int roi = bin / 49;
    const int rem = bin - roi * 49;
    const int py  = rem / 7;
    const int px  = rem - py * 7;

    const int4 r = reinterpret_cast<const int4*>(rois)[roi];
    const int x1 = r.x, y1 = r.y, x2 = r.z, y2 = r.w;

    // y coordinate (half-pixel, clipped to [0, size-1], then + start)
    const float sizy = (float)(y2 - y1);
    float cy = ((float)py + 0.5f) * (sizy / (float)POOLN) - 0.5f;
    cy = fminf(fmaxf(cy, 0.0f), sizy - 1.0f);
    const float ys = cy + (float)y1;
    const int   y0 = (int)floorf(ys);
    const int   yb = min(y0 + 1, y2 - 1);
    const float wy = ys - (float)y0;

    // x coordinate
    const float sizx = (float)(x2 - x1);
    float cx = ((float)px + 0.5f) * (sizx / (float)POOLN) - 0.5f;
    cx = fminf(fmaxf(cx, 0.0f), sizx - 1.0f);
    const float xs = cx + (float)x1;
    const int   x0 = (int)floorf(xs);
    const int   xb = min(x0 + 1, x2 - 1);
    const float wx = xs - (float)x0;

    const int coff = lane * 4;

    const f32x4 a = *reinterpret_cast<const f32x4*>(fm + (size_t)(y0 * FM_W + x0) * FM_C + coff);
    const f32x4 b = *reinterpret_cast<const f32x4*>(fm + (size_t)(y0 * FM_W + xb) * FM_C + coff);
    const f32x4 d = *reinterpret_cast<const f32x4*>(fm + (size_t)(yb * FM_W + x0) * FM_C + coff);
    const f32x4 e = *reinterpret_cast<const f32x4*>(fm + (size_t)(yb * FM_W + xb) * FM_C + coff);

    const f32x4 top = a + (b - a) * wx;
    const f32x4 bot = d + (e - d) * wx;
    const f32x4 res = top + (bot - top) * wy;

    f32x4* o = reinterpret_cast<f32x4*>(out + (size_t)bin * FM_C + coff);
    __builtin_nontemporal_store(res, o);
}

extern "C" void kernel_launch(void* const* d_in, const int* in_sizes, int n_in,
                              void* d_out, int out_size, void* d_ws, size_t ws_size,
                              hipStream_t stream) {
    const float* fm   = (const float*)d_in[0];
    const int*   rois = (const int*)d_in[1];
    float*       out  = (float*)d_out;

    const int N      = in_sizes[1] / 4;          // 1024 ROIs
    const int n_bins = N * POOLN * POOLN;        // 50176
    const int pairs  = n_bins / 2;               // 25088
    const int ppx    = pairs / NXCD;             // 3136 pairs per XCD
    dim3 grid(pairs);                            // 25088 blocks x 256 thr
    roi_align_kernel<<<grid, 256, 0, stream>>>(fm, rois, out, ppx);
}

// Round 13
// 51.789 us; speedup vs baseline: 1.2188x; 1.2188x over previous
//
#include <hip/hip_runtime.h>

// ROI-Align (bilinear, half-pixel) — B=1, H=W=128, C=512, POOL=7, N ROIs.
// Output layout: (N, 1, 7, 7, C) flat = ((roi*49 + py*7 + px) * C + c).
//
// Round-13: spatial (x-band) partition — reads L2-local AND writes contiguous.
//   Evidence matrix: reads-local+writes-scattered = 31us (R4/R8);
//   reads-scattered+writes-contiguous = 63us (R12). This kernel does both:
//   - Bins bucketed by band = x0>>4 (8 bands of 16 columns). A bin reads
//     columns {x0, x0+1} only, so band k's working set = cols [16k,16k+17)
//     x 128 rows x 512ch x 4B = 4.4 MiB -> resident in XCD k's 4 MiB L2
//     (process blocks with blockIdx%8 == k land on XCD k round-robin).
//   - Each bin processed whole: 128 lanes x f32x4 = 2 KB contiguous NT write.
//   - Banding is data-dependent: scatter pre-pass builds per-band u16 bin
//     lists in d_ws (block-aggregated atomics; output order-independent).
// ws layout: [8 x int counters, padded to 256 B][8 x n_bins x u16 lists].

#define POOLN 7
#define FM_W 128
#define FM_C 512
#define NXCD 8
#define CSLOTS 392                   // process blocks per band
#define LISTOFF 256                  // byte offset of lists in ws

typedef float f32x4 __attribute__((ext_vector_type(4)));

__global__ __launch_bounds__(256) void scatter_kernel(
    const int* __restrict__ rois,
    int* __restrict__ gcnt,
    unsigned short* __restrict__ lists,
    int n_bins)
{
    __shared__ int lcnt[NXCD];
    __shared__ int lbase[NXCD];
    const int tid = threadIdx.x;
    if (tid < NXCD) lcnt[tid] = 0;
    __syncthreads();

    const int bin = blockIdx.x * 256 + tid;
    int band = 0, rank = 0;
    if (bin < n_bins) {
        const int roi = bin / 49;
        const int rem = bin - roi * 49;
        const int py  = rem / 7;
        const int px  = rem - py * 7;
        const int4 r  = reinterpret_cast<const int4*>(rois)[roi];
        const float sizx = (float)(r.z - r.x);
        float cx = ((float)px + 0.5f) * (sizx / (float)POOLN) - 0.5f;
        cx = fminf(fmaxf(cx, 0.0f), sizx - 1.0f);
        const float xs = cx + (float)r.x;
        const int x0 = (int)floorf(xs);
        band = x0 >> 4;                       // 0..7
        rank = atomicAdd(&lcnt[band], 1);     // LDS atomic
    }
    __syncthreads();
    if (tid < NXCD) lbase[tid] = atomicAdd(&gcnt[tid], lcnt[tid]);
    __syncthreads();
    if (bin < n_bins)
        lists[band * n_bins + lbase[band] + rank] = (unsigned short)bin;
}

__global__ __launch_bounds__(256) void process_kernel(
    const float* __restrict__ fm,
    const int* __restrict__ rois,
    float* __restrict__ out,
    const int* __restrict__ gcnt,
    const unsigned short* __restrict__ lists,
    int n_bins)
{
    const int band = blockIdx.x & (NXCD - 1);   // = XCD id (round-robin)
    const int slot = blockIdx.x >> 3;           // 0..CSLOTS-1
    const int cnt  = gcnt[band];
    const unsigned short* list = lists + band * n_bins;

    const int sub  = threadIdx.x >> 7;          // 0,1 — list entry within pair
    const int lane = threadIdx.x & 127;         // f32x4 channel index
    const int coff = lane * 4;

    for (int base = slot * 2; base < cnt; base += CSLOTS * 2) {
        const int e = base + sub;
        if (e >= cnt) continue;
        const int bin = list[e];

        const int roi = bin / 49;
        const int rem = bin - roi * 49;
        const int py  = rem / 7;
        const int px  = rem - py * 7;

        const int4 r = reinterpret_cast<const int4*>(rois)[roi];
        const int x1 = r.x, y1 = r.y, x2 = r.z, y2 = r.w;

        const float sizy = (float)(y2 - y1);
        float cy = ((float)py + 0.5f) * (sizy / (float)POOLN) - 0.5f;
        cy = fminf(fmaxf(cy, 0.0f), sizy - 1.0f);
        const float ys = cy + (float)y1;
        const int   y0 = (int)floorf(ys);
        const int   yb = min(y0 + 1, y2 - 1);
        const float wy = ys - (float)y0;

        const float sizx = (float)(x2 - x1);
        float cx = ((float)px + 0.5f) * (sizx / (float)POOLN) - 0.5f;
        cx = fminf(fmaxf(cx, 0.0f), sizx - 1.0f);
        const float xs = cx + (float)x1;
        const int   x0 = (int)floorf(xs);
        const int   xb = min(x0 + 1, x2 - 1);
        const float wx = xs - (float)x0;

        const f32x4 a = *reinterpret_cast<const f32x4*>(fm + (size_t)(y0 * FM_W + x0) * FM_C + coff);
        const f32x4 b = *reinterpret_cast<const f32x4*>(fm + (size_t)(y0 * FM_W + xb) * FM_C + coff);
        const f32x4 d = *reinterpret_cast<const f32x4*>(fm + (size_t)(yb * FM_W + x0) * FM_C + coff);
        const f32x4 e4 = *reinterpret_cast<const f32x4*>(fm + (size_t)(yb * FM_W + xb) * FM_C + coff);

        const f32x4 top = a + (b - a) * wx;
        const f32x4 bot = d + (e4 - d) * wx;
        const f32x4 res = top + (bot - top) * wy;

        f32x4* o = reinterpret_cast<f32x4*>(out + (size_t)bin * FM_C + coff);
        __builtin_nontemporal_store(res, o);
    }
}

extern "C" void kernel_launch(void* const* d_in, const int* in_sizes, int n_in,
                              void* d_out, int out_size, void* d_ws, size_t ws_size,
                              hipStream_t stream) {
    const float* fm   = (const float*)d_in[0];
    const int*   rois = (const int*)d_in[1];
    float*       out  = (float*)d_out;

    const int N      = in_sizes[1] / 4;          // 1024 ROIs
    const int n_bins = N * POOLN * POOLN;        // 50176 (< 65536, fits u16)

    int*            gcnt  = (int*)d_ws;
    unsigned short* lists = (unsigned short*)((char*)d_ws + LISTOFF);

    // zero the 8 band counters (deterministic each call)
    hipMemsetAsync(d_ws, 0, LISTOFF, stream);

    const int sblocks = (n_bins + 255) / 256;    // 196
    scatter_kernel<<<sblocks, 256, 0, stream>>>(rois, gcnt, lists, n_bins);

    process_kernel<<<NXCD * CSLOTS, 256, 0, stream>>>(fm, rois, out, gcnt, lists, n_bins);
}